// Round 3
// baseline (225.707 us; speedup 1.0000x reference)
//
#include <hip/hip_runtime.h>
#include <stdint.h>

#define Tn 65536
#define Dn 768
#define NSEG 4096   // B*S = 32*128
#define NWBLK 576   // W-convert blocks appended to pool grid
#define NMBLK 16    // mask blocks appended to pool grid

typedef __bf16 bf16;
typedef __bf16 bf16x8 __attribute__((ext_vector_type(8)));
typedef float f32x4 __attribute__((ext_vector_type(4)));

__device__ inline void f4add(float4& a, const float4& v) {
  a.x += v.x; a.y += v.y; a.z += v.z; a.w += v.w;
}

// ---- Kernel 1: segment bounds only -----------------------------------------
__global__ __launch_bounds__(256) void k_prep(
    const int* __restrict__ seg, int* __restrict__ starts)
{
  const int t = blockIdx.x * 256 + threadIdx.x;     // 0..65535
  const int s = seg[t];
  const int sp = (t == 0) ? -1 : seg[t - 1];
  for (int k = sp + 1; k <= s; ++k) starts[k] = t;  // first idx with seg>=k
  if (t == Tn - 1)
    for (int k = s + 1; k <= NSEG; ++k) starts[k] = Tn;
}

// ---------------- Kernel 2: ragged mean-pool + enrich + LayerNorm -> bf16 ---
// Blocks [0,4096): one wave per sentence slot; lane owns 3 float4 (12 dims).
// Masked 8-token batches: 24 loads always in flight, no serial tail chain.
// Blocks [4096,4672): proj_w fp32->bf16 convert (rides free under the gather).
// Blocks [4672,4688): padding-mask zeros.
__global__ void k_pool_ln(
    const int* __restrict__ token_ids, const int* __restrict__ starts,
    const int* __restrict__ section_ids, const int* __restrict__ temporality_ids,
    const int* __restrict__ negation_ids, const int* __restrict__ position_ids,
    const int* __restrict__ timestamp_ids,
    const float* __restrict__ token_table, const float* __restrict__ section_table,
    const float* __restrict__ temporality_table, const float* __restrict__ negation_table,
    const float* __restrict__ position_table, const float* __restrict__ timestamp_table,
    const float* __restrict__ gamma, const float* __restrict__ beta,
    bf16* __restrict__ out_normed,
    const float* __restrict__ proj_w, bf16* __restrict__ wb,
    float* __restrict__ mask_out)
{
  const int n = blockIdx.x;
  const int lane = threadIdx.x;

  if (n >= NSEG) {
    if (n < NSEG + NWBLK) {
      // W convert: 576 blocks x 64 lanes x 4 float4 = 147456 float4
      const int base = ((n - NSEG) * 64 + lane) * 4;
      #pragma unroll
      for (int u = 0; u < 4; ++u) {
        const float4 v = ((const float4*)proj_w)[base + u];
        alignas(8) bf16 o[4] = {(bf16)v.x, (bf16)v.y, (bf16)v.z, (bf16)v.w};
        ((ushort4*)wb)[base + u] = *(ushort4*)o;
      }
    } else {
      // mask zeros: 16 blocks x 64 lanes x float4 = 4096 floats
      ((float4*)mask_out)[(n - NSEG - NWBLK) * 64 + lane] =
          make_float4(0.f, 0.f, 0.f, 0.f);
    }
    return;
  }

  const int start = starts[n];
  const int end   = starts[n + 1];
  const float scale = 1.0f / fmaxf((float)(end - start), 1.0f);

  const float4* tt = (const float4*)token_table;   // row stride = 192 float4

  // enrichment rows (issued early; ids are wave-uniform scalar loads)
  const float4* e1 = (const float4*)(section_table     + (size_t)section_ids[n]     * Dn);
  const float4* e2 = (const float4*)(temporality_table + (size_t)temporality_ids[n] * Dn);
  const float4* e3 = (const float4*)(negation_table    + (size_t)negation_ids[n]    * Dn);
  const float4* e4 = (const float4*)(position_table    + (size_t)position_ids[n]    * Dn);
  const float4* e5 = (const float4*)(timestamp_table   + (size_t)timestamp_ids[n]   * Dn);
  float4 en[3];
  #pragma unroll
  for (int j = 0; j < 3; ++j) {
    const int d = j * 64 + lane;
    float4 q = e1[d];
    f4add(q, e2[d]); f4add(q, e3[d]); f4add(q, e4[d]); f4add(q, e5[d]);
    en[j] = q;
  }

  float4 acc[3];
  #pragma unroll
  for (int j = 0; j < 3; ++j) acc[j] = make_float4(0.f, 0.f, 0.f, 0.f);

  // masked 8-token batches: always issue all 24 row loads (ids clamped to
  // valid indices), then accumulate only the first (end - t) of them via
  // wave-uniform branches. No dependent serial tail.
  int t = start;
  int ids[8];
  #pragma unroll
  for (int u = 0; u < 8; ++u)
    ids[u] = token_ids[(t + u < Tn) ? t + u : Tn - 1];

  while (t < end) {
    float4 L[8][3];
    #pragma unroll
    for (int u = 0; u < 8; ++u) {
      const float4* r = tt + (size_t)ids[u] * 192;
      #pragma unroll
      for (int j = 0; j < 3; ++j) L[u][j] = r[j * 64 + lane];
    }
    const int nb = end - t;    // wave-uniform
    t += 8;
    // prefetch next batch's ids while the 24 loads are in flight
    #pragma unroll
    for (int u = 0; u < 8; ++u)
      ids[u] = token_ids[(t + u < Tn) ? t + u : Tn - 1];
    if (nb >= 8) {
      #pragma unroll
      for (int j = 0; j < 3; ++j) {
        f4add(L[0][j], L[1][j]); f4add(L[2][j], L[3][j]);
        f4add(L[4][j], L[5][j]); f4add(L[6][j], L[7][j]);
        f4add(L[0][j], L[2][j]); f4add(L[4][j], L[6][j]);
        f4add(L[0][j], L[4][j]); f4add(acc[j], L[0][j]);
      }
    } else {
      #pragma unroll
      for (int u = 0; u < 8; ++u) {
        if (u < nb) {
          #pragma unroll
          for (int j = 0; j < 3; ++j) f4add(acc[j], L[u][j]);
        }
      }
    }
  }

  float4 e[3];
  #pragma unroll
  for (int j = 0; j < 3; ++j) {
    e[j].x = acc[j].x * scale + en[j].x;
    e[j].y = acc[j].y * scale + en[j].y;
    e[j].z = acc[j].z * scale + en[j].z;
    e[j].w = acc[j].w * scale + en[j].w;
  }

  // LayerNorm via wave butterfly (all lanes end with the total)
  float s = 0.f;
  #pragma unroll
  for (int j = 0; j < 3; ++j) s += e[j].x + e[j].y + e[j].z + e[j].w;
  #pragma unroll
  for (int o = 32; o > 0; o >>= 1) s += __shfl_xor(s, o, 64);
  const float mu = s * (1.0f / 768.0f);

  float v = 0.f;
  #pragma unroll
  for (int j = 0; j < 3; ++j) {
    e[j].x -= mu; e[j].y -= mu; e[j].z -= mu; e[j].w -= mu;
    v += e[j].x * e[j].x + e[j].y * e[j].y + e[j].z * e[j].z + e[j].w * e[j].w;
  }
  #pragma unroll
  for (int o = 32; o > 0; o >>= 1) v += __shfl_xor(v, o, 64);
  const float inv = rsqrtf(v * (1.0f / 768.0f) + 1e-5f);

  #pragma unroll
  for (int j = 0; j < 3; ++j) {
    const int d = j * 64 + lane;
    const float4 g = ((const float4*)gamma)[d];
    const float4 b = ((const float4*)beta)[d];
    alignas(8) bf16 o[4];
    o[0] = (bf16)(e[j].x * inv * g.x + b.x);
    o[1] = (bf16)(e[j].y * inv * g.y + b.y);
    o[2] = (bf16)(e[j].z * inv * g.z + b.z);
    o[3] = (bf16)(e[j].w * inv * g.w + b.w);
    *(ushort4*)(out_normed + (size_t)n * Dn + 4 * d) = *(ushort4*)o;
  }
}

// ------------- Kernel 3: out = normed @ W^T + bias  (bf16 MFMA) -------------
// m97-class structure: BM=128, BN=128, BK=32, 4 waves (2x2, 64x64 each),
// 16 MFMA per wave per K-step, global_load_lds width-16 staging.
// grid (768/128, 4096/128) = (6, 32) = 192 blocks.
__global__ __launch_bounds__(256) void k_gemm(
    const bf16* __restrict__ A, const bf16* __restrict__ W,
    const float* __restrict__ bias, float* __restrict__ out)
{
  __shared__ bf16 As[128 * 32];   // 8 KB
  __shared__ bf16 Bs[128 * 32];   // 8 KB
  const int tid  = threadIdx.x;
  const int lane = tid & 63;
  const int w    = tid >> 6;
  const int m0 = blockIdx.y * 128;
  const int n0 = blockIdx.x * 128;
  const int wm = (w >> 1) * 64;
  const int wn = (w & 1) * 64;

  f32x4 acc[4][4];
  #pragma unroll
  for (int i = 0; i < 4; ++i)
    #pragma unroll
    for (int j = 0; j < 4; ++j) acc[i][j] = (f32x4){0.f, 0.f, 0.f, 0.f};

  const int sr = tid >> 2;          // row 0..63 (second issue adds +64)
  const int sc = (tid & 3) * 8;     // element offset within K=32
  const bf16* a0 = A + (size_t)(m0 + sr) * 768 + sc;
  const bf16* a1 = a0 + (size_t)64 * 768;
  const bf16* b0 = W + (size_t)(n0 + sr) * 768 + sc;
  const bf16* b1 = b0 + (size_t)64 * 768;

  for (int kt = 0; kt < 24; ++kt) {
    const int ko = kt * 32;
    __syncthreads();
    __builtin_amdgcn_global_load_lds(
        (const __attribute__((address_space(1))) void*)(a0 + ko),
        (__attribute__((address_space(3))) void*)(As + tid * 8), 16, 0, 0);
    __builtin_amdgcn_global_load_lds(
        (const __attribute__((address_space(1))) void*)(a1 + ko),
        (__attribute__((address_space(3))) void*)(As + (256 + tid) * 8), 16, 0, 0);
    __builtin_amdgcn_global_load_lds(
        (const __attribute__((address_space(1))) void*)(b0 + ko),
        (__attribute__((address_space(3))) void*)(Bs + tid * 8), 16, 0, 0);
    __builtin_amdgcn_global_load_lds(
        (const __attribute__((address_space(1))) void*)(b1 + ko),
        (__attribute__((address_space(3))) void*)(Bs + (256 + tid) * 8), 16, 0, 0);
    __syncthreads();

    bf16x8 af[4], bfr[4];
    #pragma unroll
    for (int i = 0; i < 4; ++i)
      af[i] = *(const bf16x8*)(As + (wm + i * 16 + (lane & 15)) * 32 + (lane >> 4) * 8);
    #pragma unroll
    for (int j = 0; j < 4; ++j)
      bfr[j] = *(const bf16x8*)(Bs + (wn + j * 16 + (lane & 15)) * 32 + (lane >> 4) * 8);

    #pragma unroll
    for (int i = 0; i < 4; ++i)
      #pragma unroll
      for (int j = 0; j < 4; ++j)
        acc[i][j] = __builtin_amdgcn_mfma_f32_16x16x32_bf16(af[i], bfr[j], acc[i][j], 0, 0, 0);
  }

  float bvals[4];
  #pragma unroll
  for (int j = 0; j < 4; ++j) bvals[j] = bias[n0 + wn + j * 16 + (lane & 15)];
  const int r0 = (lane >> 4) * 4;
  #pragma unroll
  for (int i = 0; i < 4; ++i) {
    #pragma unroll
    for (int r = 0; r < 4; ++r) {
      const int gm = m0 + wm + i * 16 + r0 + r;
      float* orow = out + (size_t)gm * 768 + n0 + wn;
      #pragma unroll
      for (int j = 0; j < 4; ++j)
        orow[j * 16 + (lane & 15)] = acc[i][j][r] + bvals[j];
    }
  }
}

extern "C" void kernel_launch(void* const* d_in, const int* in_sizes, int n_in,
                              void* d_out, int out_size, void* d_ws, size_t ws_size,
                              hipStream_t stream) {
  const int* token_ids       = (const int*)d_in[0];
  const int* segment_ids     = (const int*)d_in[1];
  const int* section_ids     = (const int*)d_in[2];
  const int* temporality_ids = (const int*)d_in[3];
  const int* negation_ids    = (const int*)d_in[4];
  const int* position_ids    = (const int*)d_in[5];
  const int* timestamp_ids   = (const int*)d_in[6];
  const float* token_table       = (const float*)d_in[7];
  const float* section_table     = (const float*)d_in[8];
  const float* temporality_table = (const float*)d_in[9];
  const float* negation_table    = (const float*)d_in[10];
  const float* position_table    = (const float*)d_in[11];
  const float* timestamp_table   = (const float*)d_in[12];
  const float* ln_gamma = (const float*)d_in[13];
  const float* ln_beta  = (const float*)d_in[14];
  const float* proj_w   = (const float*)d_in[15];
  const float* proj_b   = (const float*)d_in[16];

  float* out = (float*)d_out;
  bf16* wsW = (bf16*)d_ws;                        // 768*768 bf16   (1.18 MB)
  bf16* wsN = wsW + (size_t)Dn * Dn;              // 4096*768 bf16  (6.29 MB)
  int*  wsS = (int*)((char*)d_ws + (size_t)(Dn * Dn + NSEG * Dn) * 2);  // 4097 ints

  // segment bounds only
  k_prep<<<256, 256, 0, stream>>>(segment_ids, wsS);
  // pool + enrich + LN -> bf16 normed; also W->bf16 convert + mask zeros
  k_pool_ln<<<NSEG + NWBLK + NMBLK, 64, 0, stream>>>(token_ids, wsS, section_ids,
      temporality_ids, negation_ids, position_ids, timestamp_ids,
      token_table, section_table, temporality_table, negation_table,
      position_table, timestamp_table, ln_gamma, ln_beta, wsN,
      proj_w, wsW, out + (size_t)NSEG * Dn);
  // projection GEMM + bias (128x128 tile, m97 structure)
  k_gemm<<<dim3(6, 32), 256, 0, stream>>>(wsN, wsW, proj_b, out);
}

// Round 4
// 202.610 us; speedup vs baseline: 1.1140x; 1.1140x over previous
//
#include <hip/hip_runtime.h>
#include <stdint.h>

#define Tn 65536
#define Dn 768
#define NSEG 4096   // B*S = 32*128

typedef __bf16 bf16;
typedef __bf16 bf16x8 __attribute__((ext_vector_type(8)));
typedef float f32x4 __attribute__((ext_vector_type(4)));

__device__ inline void f4add(float4& a, const float4& v) {
  a.x += v.x; a.y += v.y; a.z += v.z; a.w += v.w;
}

// ---- Kernel 1: proj_w fp32->bf16  +  padding-mask zeros  +  segment bounds -
// blocks [0,576): convert W; [576,592): zero mask; [592,848): segment starts.
__global__ __launch_bounds__(256) void k_prep(
    const float* __restrict__ w, bf16* __restrict__ wb,
    float* __restrict__ mask_out,
    const int* __restrict__ seg, int* __restrict__ starts)
{
  const int b = blockIdx.x;
  if (b < 576) {
    const int i = b * 256 + threadIdx.x;   // 147456 threads, 4 elems each
    const float4 v = ((const float4*)w)[i];
    alignas(8) bf16 o[4] = {(bf16)v.x, (bf16)v.y, (bf16)v.z, (bf16)v.w};
    ((ushort4*)wb)[i] = *(ushort4*)o;
  } else if (b < 592) {
    mask_out[(b - 576) * 256 + threadIdx.x] = 0.0f;   // 16x256 = 4096
  } else {
    const int t = (b - 592) * 256 + threadIdx.x;      // 0..65535
    const int s = seg[t];
    const int sp = (t == 0) ? -1 : seg[t - 1];
    for (int k = sp + 1; k <= s; ++k) starts[k] = t;  // first idx with seg>=k
    if (t == Tn - 1)
      for (int k = s + 1; k <= NSEG; ++k) starts[k] = Tn;
  }
}

// ---------------- Kernel 2: ragged mean-pool + enrich + LayerNorm -> bf16 ---
// One wave per sentence slot; lane owns 3 float4 (12 dims). No __syncthreads.
// 8-token batches: 24 outstanding 16B loads/lane; next batch's ids prefetched
// (wave-uniform -> SGPRs) before the accumulate tree consumes the loads.
__global__ void k_pool_ln(
    const int* __restrict__ token_ids, const int* __restrict__ starts,
    const int* __restrict__ section_ids, const int* __restrict__ temporality_ids,
    const int* __restrict__ negation_ids, const int* __restrict__ position_ids,
    const int* __restrict__ timestamp_ids,
    const float* __restrict__ token_table, const float* __restrict__ section_table,
    const float* __restrict__ temporality_table, const float* __restrict__ negation_table,
    const float* __restrict__ position_table, const float* __restrict__ timestamp_table,
    const float* __restrict__ gamma, const float* __restrict__ beta,
    bf16* __restrict__ out_normed)
{
  const int n = blockIdx.x;
  const int lane = threadIdx.x;
  const int start = starts[n];
  const int end   = starts[n + 1];
  const float scale = 1.0f / fmaxf((float)(end - start), 1.0f);

  const float4* tt = (const float4*)token_table;   // row stride = 192 float4

  // enrichment rows (issued early; ids are wave-uniform scalar loads)
  const float4* e1 = (const float4*)(section_table     + (size_t)section_ids[n]     * Dn);
  const float4* e2 = (const float4*)(temporality_table + (size_t)temporality_ids[n] * Dn);
  const float4* e3 = (const float4*)(negation_table    + (size_t)negation_ids[n]    * Dn);
  const float4* e4 = (const float4*)(position_table    + (size_t)position_ids[n]    * Dn);
  const float4* e5 = (const float4*)(timestamp_table   + (size_t)timestamp_ids[n]   * Dn);
  float4 en[3];
  #pragma unroll
  for (int j = 0; j < 3; ++j) {
    const int d = j * 64 + lane;
    float4 q = e1[d];
    f4add(q, e2[d]); f4add(q, e3[d]); f4add(q, e4[d]); f4add(q, e5[d]);
    en[j] = q;
  }

  float4 acc[3];
  #pragma unroll
  for (int j = 0; j < 3; ++j) acc[j] = make_float4(0.f, 0.f, 0.f, 0.f);

  // ids for the first batch (clamped so prefetch never reads OOB)
  int t = start;
  int ids[8];
  #pragma unroll
  for (int u = 0; u < 8; ++u)
    ids[u] = token_ids[(t + u < Tn) ? t + u : Tn - 1];

  while (t + 8 <= end) {
    float4 L[8][3];
    #pragma unroll
    for (int u = 0; u < 8; ++u) {
      const float4* r = tt + (size_t)ids[u] * 192;
      #pragma unroll
      for (int j = 0; j < 3; ++j) L[u][j] = r[j * 64 + lane];
    }
    t += 8;
    // prefetch next batch's ids while the 24 loads are in flight
    #pragma unroll
    for (int u = 0; u < 8; ++u)
      ids[u] = token_ids[(t + u < Tn) ? t + u : Tn - 1];
    #pragma unroll
    for (int j = 0; j < 3; ++j) {
      f4add(L[0][j], L[1][j]); f4add(L[2][j], L[3][j]);
      f4add(L[4][j], L[5][j]); f4add(L[6][j], L[7][j]);
      f4add(L[0][j], L[2][j]); f4add(L[4][j], L[6][j]);
      f4add(L[0][j], L[4][j]); f4add(acc[j], L[0][j]);
    }
  }
  // tail (<8 tokens): ids[] already holds ids for t..t+7
  for (int u = 0; t < end; ++t, ++u) {
    const float4* r = tt + (size_t)ids[u] * 192;
    #pragma unroll
    for (int j = 0; j < 3; ++j) f4add(acc[j], r[j * 64 + lane]);
  }

  float4 e[3];
  #pragma unroll
  for (int j = 0; j < 3; ++j) {
    e[j].x = acc[j].x * scale + en[j].x;
    e[j].y = acc[j].y * scale + en[j].y;
    e[j].z = acc[j].z * scale + en[j].z;
    e[j].w = acc[j].w * scale + en[j].w;
  }

  // LayerNorm via wave butterfly (all lanes end with the total)
  float s = 0.f;
  #pragma unroll
  for (int j = 0; j < 3; ++j) s += e[j].x + e[j].y + e[j].z + e[j].w;
  #pragma unroll
  for (int o = 32; o > 0; o >>= 1) s += __shfl_xor(s, o, 64);
  const float mu = s * (1.0f / 768.0f);

  float v = 0.f;
  #pragma unroll
  for (int j = 0; j < 3; ++j) {
    e[j].x -= mu; e[j].y -= mu; e[j].z -= mu; e[j].w -= mu;
    v += e[j].x * e[j].x + e[j].y * e[j].y + e[j].z * e[j].z + e[j].w * e[j].w;
  }
  #pragma unroll
  for (int o = 32; o > 0; o >>= 1) v += __shfl_xor(v, o, 64);
  const float inv = rsqrtf(v * (1.0f / 768.0f) + 1e-5f);

  #pragma unroll
  for (int j = 0; j < 3; ++j) {
    const int d = j * 64 + lane;
    const float4 g = ((const float4*)gamma)[d];
    const float4 b = ((const float4*)beta)[d];
    alignas(8) bf16 o[4];
    o[0] = (bf16)(e[j].x * inv * g.x + b.x);
    o[1] = (bf16)(e[j].y * inv * g.y + b.y);
    o[2] = (bf16)(e[j].z * inv * g.z + b.z);
    o[3] = (bf16)(e[j].w * inv * g.w + b.w);
    *(ushort4*)(out_normed + (size_t)n * Dn + 4 * d) = *(ushort4*)o;
  }
}

// ------------- Kernel 3: out = normed @ W^T + bias  (bf16 MFMA) -------------
// A: [4096,768] bf16 row-major.  W: [768,768] bf16 row-major ([e][d] = [N][K]).
// BM=64, BN=128, BK=32 -> grid 6x64 = 384 blocks.
__global__ __launch_bounds__(256) void k_gemm(
    const bf16* __restrict__ A, const bf16* __restrict__ W,
    const float* __restrict__ bias, float* __restrict__ out)
{
  __shared__ bf16 As[64 * 32];    // 4 KB
  __shared__ bf16 Bs[128 * 32];   // 8 KB
  const int tid  = threadIdx.x;
  const int lane = tid & 63;
  const int w    = tid >> 6;
  const int m0 = blockIdx.y * 64;
  const int n0 = blockIdx.x * 128;
  const int wm = (w >> 1) * 32;
  const int wn = (w & 1) * 64;

  f32x4 acc[2][4];
  #pragma unroll
  for (int i = 0; i < 2; ++i)
    #pragma unroll
    for (int j = 0; j < 4; ++j) acc[i][j] = (f32x4){0.f, 0.f, 0.f, 0.f};

  const int fr = tid >> 2;
  const int fc = (tid & 3) * 8;
  const bf16* agp = A + (size_t)(m0 + fr) * 768 + fc;
  const bf16* bgp = W + (size_t)(n0 + fr) * 768 + fc;

  for (int kt = 0; kt < 24; ++kt) {
    __syncthreads();
    __builtin_amdgcn_global_load_lds(
        (const __attribute__((address_space(1))) void*)(agp + kt * 32),
        (__attribute__((address_space(3))) void*)(As + tid * 8), 16, 0, 0);
    #pragma unroll
    for (int it = 0; it < 2; ++it) {
      const int f = it * 256 + tid;
      __builtin_amdgcn_global_load_lds(
          (const __attribute__((address_space(1))) void*)(bgp + (size_t)it * 64 * 768 + kt * 32),
          (__attribute__((address_space(3))) void*)(Bs + f * 8), 16, 0, 0);
    }
    __syncthreads();

    bf16x8 af[2], bfr[4];
    #pragma unroll
    for (int i = 0; i < 2; ++i)
      af[i] = *(const bf16x8*)(As + (wm + i * 16 + (lane & 15)) * 32 + (lane >> 4) * 8);
    #pragma unroll
    for (int j = 0; j < 4; ++j)
      bfr[j] = *(const bf16x8*)(Bs + (wn + j * 16 + (lane & 15)) * 32 + (lane >> 4) * 8);

    #pragma unroll
    for (int i = 0; i < 2; ++i)
      #pragma unroll
      for (int j = 0; j < 4; ++j)
        acc[i][j] = __builtin_amdgcn_mfma_f32_16x16x32_bf16(af[i], bfr[j], acc[i][j], 0, 0, 0);
  }

  float bvals[4];
  #pragma unroll
  for (int j = 0; j < 4; ++j) bvals[j] = bias[n0 + wn + j * 16 + (lane & 15)];
  const int r0 = (lane >> 4) * 4;
  #pragma unroll
  for (int i = 0; i < 2; ++i) {
    #pragma unroll
    for (int r = 0; r < 4; ++r) {
      const int gm = m0 + wm + i * 16 + r0 + r;
      float* orow = out + (size_t)gm * 768 + n0 + wn;
      #pragma unroll
      for (int j = 0; j < 4; ++j)
        orow[j * 16 + (lane & 15)] = acc[i][j][r] + bvals[j];
    }
  }
}

extern "C" void kernel_launch(void* const* d_in, const int* in_sizes, int n_in,
                              void* d_out, int out_size, void* d_ws, size_t ws_size,
                              hipStream_t stream) {
  const int* token_ids       = (const int*)d_in[0];
  const int* segment_ids     = (const int*)d_in[1];
  const int* section_ids     = (const int*)d_in[2];
  const int* temporality_ids = (const int*)d_in[3];
  const int* negation_ids    = (const int*)d_in[4];
  const int* position_ids    = (const int*)d_in[5];
  const int* timestamp_ids   = (const int*)d_in[6];
  const float* token_table       = (const float*)d_in[7];
  const float* section_table     = (const float*)d_in[8];
  const float* temporality_table = (const float*)d_in[9];
  const float* negation_table    = (const float*)d_in[10];
  const float* position_table    = (const float*)d_in[11];
  const float* timestamp_table   = (const float*)d_in[12];
  const float* ln_gamma = (const float*)d_in[13];
  const float* ln_beta  = (const float*)d_in[14];
  const float* proj_w   = (const float*)d_in[15];
  const float* proj_b   = (const float*)d_in[16];

  float* out = (float*)d_out;
  bf16* wsW = (bf16*)d_ws;                        // 768*768 bf16   (1.18 MB)
  bf16* wsN = wsW + (size_t)Dn * Dn;              // 4096*768 bf16  (6.29 MB)
  int*  wsS = (int*)((char*)d_ws + (size_t)(Dn * Dn + NSEG * Dn) * 2);  // 4097 ints

  // W->bf16 (576) + mask zeros (16) + segment bounds (256)
  k_prep<<<848, 256, 0, stream>>>(proj_w, wsW, out + (size_t)NSEG * Dn,
                                  segment_ids, wsS);
  // pool + enrich + LN -> bf16 normed (one wave per segment)
  k_pool_ln<<<NSEG, 64, 0, stream>>>(token_ids, wsS, section_ids,
      temporality_ids, negation_ids, position_ids, timestamp_ids,
      token_table, section_table, temporality_table, negation_table,
      position_table, timestamp_table, ln_gamma, ln_beta, wsN);
  // projection GEMM + bias
  k_gemm<<<dim3(6, 64), 256, 0, stream>>>(wsN, wsW, proj_b, out);
}